// Round 1
// baseline (409.804 us; speedup 1.0000x reference)
//
#include <hip/hip_runtime.h>

#define H   8
#define DK  64
#define DV  64
#define DM  512
#define B_  8
#define LQ  512
#define LK  1024
#define NEG (-1e30f)

typedef __attribute__((ext_vector_type(8))) short bf16x8;
typedef __attribute__((ext_vector_type(4))) float f32x4;

__device__ __forceinline__ short f2bf(float f) {
    union { float f; unsigned u; } x; x.f = f;
    unsigned r = x.u + 0x7fffu + ((x.u >> 16) & 1u);
    return (short)(r >> 16);
}

// ---------------- kernel 1: cast + transpose the 4 weight matrices ----------
// WT[mat][n][k] = bf16(w[mat][k][n]),  each 512x512
__global__ __launch_bounds__(256) void castw_kernel(
    const float* __restrict__ wqs, const float* __restrict__ wks,
    const float* __restrict__ wvs, const float* __restrict__ wfc,
    short* __restrict__ WT) {
    __shared__ float tile[32][33];
    int mat = blockIdx.z;
    const float* src = (mat == 0) ? wqs : (mat == 1) ? wks : (mat == 2) ? wvs : wfc;
    short* dst = WT + (size_t)mat * DM * DM;
    int k0 = blockIdx.x * 32, n0 = blockIdx.y * 32;
    int tx = threadIdx.x, ty = threadIdx.y;
#pragma unroll
    for (int i = 0; i < 4; i++)
        tile[ty + i * 8][tx] = src[(size_t)(k0 + ty + i * 8) * DM + n0 + tx];
    __syncthreads();
#pragma unroll
    for (int i = 0; i < 4; i++)
        dst[(size_t)(n0 + ty + i * 8) * DM + k0 + tx] = f2bf(tile[tx][ty + i * 8]);
}

// ---------------- kernel 2: transpose + log the attention prior -------------
// logp[b][q][k] = logf(prior[b][k][q] + 1e-8)
__global__ __launch_bounds__(256) void prior_kernel(
    const float* __restrict__ prior, float* __restrict__ logp) {
    __shared__ float tile[32][33];
    int b = blockIdx.z, k0 = blockIdx.x * 32, q0 = blockIdx.y * 32;
    int tx = threadIdx.x, ty = threadIdx.y;
    const float* src = prior + (size_t)b * LK * LQ;
    float* dst = logp + (size_t)b * LQ * LK;
#pragma unroll
    for (int i = 0; i < 4; i++)
        tile[ty + i * 8][tx] = src[(size_t)(k0 + ty + i * 8) * LQ + q0 + tx];
    __syncthreads();
#pragma unroll
    for (int i = 0; i < 4; i++)
        dst[(size_t)(q0 + ty + i * 8) * LK + k0 + tx] = logf(tile[tx][ty + i * 8] + 1e-8f);
}

// ---------------- kernel 3: projections (X fp32 @ WT^T) -> bf16 -------------
// MODE 0: out[row][col] natural (ld = 512)
// MODE 1: V transposed per-head: out[((col/64)*B + row/1024)*64 + col%64][row%1024]
template <int MODE>
__global__ __launch_bounds__(256) void proj_kernel(
    const float* __restrict__ X, const short* __restrict__ WT,
    short* __restrict__ out) {
    int tid = threadIdx.x;
    int wid = tid >> 6, lane = tid & 63, g = lane >> 4, ln = lane & 15;
    int wr = wid >> 1, wc = wid & 1;
    int r0 = blockIdx.x * 64, c0 = blockIdx.y * 64;
    f32x4 acc[2][2] = {};
    for (int kb = 0; kb < 16; kb++) {
        bf16x8 a[2], b[2];
#pragma unroll
        for (int i = 0; i < 2; i++) {
            int row = r0 + wr * 32 + i * 16 + ln;
            const float* xp = X + (size_t)row * DM + kb * 32 + g * 8;
            float4 x0 = *(const float4*)xp;
            float4 x1 = *(const float4*)(xp + 4);
            bf16x8 av;
            av[0] = f2bf(x0.x); av[1] = f2bf(x0.y); av[2] = f2bf(x0.z); av[3] = f2bf(x0.w);
            av[4] = f2bf(x1.x); av[5] = f2bf(x1.y); av[6] = f2bf(x1.z); av[7] = f2bf(x1.w);
            a[i] = av;
        }
#pragma unroll
        for (int j = 0; j < 2; j++) {
            int col = c0 + wc * 32 + j * 16 + ln;
            b[j] = *(const bf16x8*)(WT + (size_t)col * DM + kb * 32 + g * 8);
        }
#pragma unroll
        for (int i = 0; i < 2; i++)
#pragma unroll
            for (int j = 0; j < 2; j++)
                acc[i][j] = __builtin_amdgcn_mfma_f32_16x16x32_bf16(a[i], b[j], acc[i][j], 0, 0, 0);
    }
#pragma unroll
    for (int i = 0; i < 2; i++)
#pragma unroll
        for (int j = 0; j < 2; j++) {
            int colg = c0 + wc * 32 + j * 16 + ln;
            if (MODE == 0) {
#pragma unroll
                for (int r = 0; r < 4; r++) {
                    int rowg = r0 + wr * 32 + i * 16 + g * 4 + r;
                    out[(size_t)rowg * DM + colg] = f2bf(acc[i][j][r]);
                }
            } else {
                int hh = colg >> 6, d = colg & 63;
                int rbase = r0 + wr * 32 + i * 16 + g * 4;
                int bb = rbase >> 10, kk = rbase & 1023;
                union { short s[4]; unsigned long long u; } pk;
#pragma unroll
                for (int r = 0; r < 4; r++) pk.s[r] = f2bf(acc[i][j][r]);
                *(unsigned long long*)(out + ((size_t)((hh * B_ + bb) * DV + d)) * LK + kk) = pk.u;
            }
        }
}

// ---------------- kernel 4: fused attention ---------------------------------
__global__ __launch_bounds__(256) void attn_kernel(
    const short* __restrict__ QHb, const short* __restrict__ KHb,
    const short* __restrict__ VT, const float* __restrict__ logp,
    const float* __restrict__ km, const float* __restrict__ qm,
    const float* __restrict__ mm, float* __restrict__ p_out,
    float* __restrict__ raw_out, float* __restrict__ lgp_out,
    short* __restrict__ outh) {
    __shared__ short ptile[16][LK + 8];
    __shared__ float red[4][16][2];
    int tid = threadIdx.x;
    int wid = tid >> 6, lane = tid & 63, g = lane >> 4, ln = lane & 15;
    int q0 = blockIdx.x * 16, b = blockIdx.y, h = blockIdx.z;
    int kw0 = wid * 256;

    bf16x8 aq[2];
#pragma unroll
    for (int i = 0; i < 2; i++)
        aq[i] = *(const bf16x8*)(QHb + ((size_t)(b * LQ + q0 + ln)) * DM + h * DK + i * 32 + g * 8);

    const size_t mrow = ((size_t)b * LQ + q0) * LK;

    // ---- pass 1: denominators with fixed stabilizer m = 16 ----
    float s1[4] = {0.f, 0.f, 0.f, 0.f}, s2[4] = {0.f, 0.f, 0.f, 0.f};
    for (int kt = 0; kt < 16; kt++) {
        int k0 = kw0 + kt * 16;
        const short* kp = KHb + ((size_t)(b * LK + k0 + ln)) * DM + h * DK + g * 8;
        bf16x8 bk0 = *(const bf16x8*)kp;
        bf16x8 bk1 = *(const bf16x8*)(kp + 32);
        f32x4 sa = {0.f, 0.f, 0.f, 0.f};
        sa = __builtin_amdgcn_mfma_f32_16x16x32_bf16(aq[0], bk0, sa, 0, 0, 0);
        sa = __builtin_amdgcn_mfma_f32_16x16x32_bf16(aq[1], bk1, sa, 0, 0, 0);
        int kcol = k0 + ln;
#pragma unroll
        for (int r = 0; r < 4; r++) {
            size_t idx = mrow + (size_t)(g * 4 + r) * LK + kcol;
            float s = (km[idx] == 0.0f) ? NEG : sa[r] * 0.125f;
            float t = s + logp[idx];
            s1[r] += __expf(s - 16.0f);
            s2[r] += __expf(t - 16.0f);
        }
    }
#pragma unroll
    for (int m = 1; m < 16; m <<= 1)
#pragma unroll
        for (int r = 0; r < 4; r++) {
            s1[r] += __shfl_xor(s1[r], m, 64);
            s2[r] += __shfl_xor(s2[r], m, 64);
        }
    if (ln == 0)
#pragma unroll
        for (int r = 0; r < 4; r++) {
            red[wid][g * 4 + r][0] = s1[r];
            red[wid][g * 4 + r][1] = s2[r];
        }
    __syncthreads();
    float lse1[4], lse2[4], qmv[4];
#pragma unroll
    for (int r = 0; r < 4; r++) {
        int row = g * 4 + r;
        float t1 = red[0][row][0] + red[1][row][0] + red[2][row][0] + red[3][row][0];
        float t2 = red[0][row][1] + red[1][row][1] + red[2][row][1] + red[3][row][1];
        lse1[r] = 16.0f + logf(t1);
        lse2[r] = 16.0f + logf(t2);
        qmv[r] = qm[b * LQ + q0 + row];
    }

    // ---- pass 2: recompute scores, write the 3 attention outputs + p tile ----
    const size_t obase = ((size_t)(h * B_ + b) * LQ + q0) * LK;
    for (int kt = 0; kt < 16; kt++) {
        int k0 = kw0 + kt * 16;
        const short* kp = KHb + ((size_t)(b * LK + k0 + ln)) * DM + h * DK + g * 8;
        bf16x8 bk0 = *(const bf16x8*)kp;
        bf16x8 bk1 = *(const bf16x8*)(kp + 32);
        f32x4 sa = {0.f, 0.f, 0.f, 0.f};
        sa = __builtin_amdgcn_mfma_f32_16x16x32_bf16(aq[0], bk0, sa, 0, 0, 0);
        sa = __builtin_amdgcn_mfma_f32_16x16x32_bf16(aq[1], bk1, sa, 0, 0, 0);
        int kcol = k0 + ln;
#pragma unroll
        for (int r = 0; r < 4; r++) {
            size_t idx = mrow + (size_t)(g * 4 + r) * LK + kcol;
            float s = (km[idx] == 0.0f) ? NEG : sa[r] * 0.125f;
            float t = s + logp[idx];
            size_t oidx = obase + (size_t)(g * 4 + r) * LK + kcol;
            lgp_out[oidx] = t - lse1[r];
            float p0 = __expf(t - lse2[r]);
            float praw = p0 * qmv[r];
            float pfin = praw * mm[idx];
            raw_out[oidx] = praw;
            p_out[oidx] = pfin;
            ptile[g * 4 + r][kcol] = f2bf(pfin);
        }
    }
    __syncthreads();

    // ---- PV: each wave owns a 16-wide d-slice, full K ----
    f32x4 oacc = {0.f, 0.f, 0.f, 0.f};
    int d0 = wid * 16;
    const short* vrow = VT + ((size_t)((h * B_ + b) * DV + d0 + ln)) * LK;
    for (int kc = 0; kc < 32; kc++) {
        bf16x8 ap = *(const bf16x8*)(&ptile[ln][kc * 32 + g * 8]);
        bf16x8 bv = *(const bf16x8*)(vrow + kc * 32 + g * 8);
        oacc = __builtin_amdgcn_mfma_f32_16x16x32_bf16(ap, bv, oacc, 0, 0, 0);
    }
#pragma unroll
    for (int r = 0; r < 4; r++) {
        int row = q0 + g * 4 + r;
        outh[((size_t)(b * LQ + row)) * DM + h * DV + d0 + ln] = f2bf(oacc[r]);
    }
}

// ---------------- kernel 5: out = outh @ w_fc + residual --------------------
__global__ __launch_bounds__(256) void final_kernel(
    const short* __restrict__ outh, const short* __restrict__ WTfc,
    const float* __restrict__ qres, float* __restrict__ out) {
    int tid = threadIdx.x;
    int wid = tid >> 6, lane = tid & 63, g = lane >> 4, ln = lane & 15;
    int wr = wid >> 1, wc = wid & 1;
    int r0 = blockIdx.x * 64, c0 = blockIdx.y * 64;
    f32x4 acc[2][2] = {};
    for (int kb = 0; kb < 16; kb++) {
        bf16x8 a[2], b[2];
#pragma unroll
        for (int i = 0; i < 2; i++)
            a[i] = *(const bf16x8*)(outh + ((size_t)(r0 + wr * 32 + i * 16 + ln)) * DM + kb * 32 + g * 8);
#pragma unroll
        for (int j = 0; j < 2; j++)
            b[j] = *(const bf16x8*)(WTfc + ((size_t)(c0 + wc * 32 + j * 16 + ln)) * DM + kb * 32 + g * 8);
#pragma unroll
        for (int i = 0; i < 2; i++)
#pragma unroll
            for (int j = 0; j < 2; j++)
                acc[i][j] = __builtin_amdgcn_mfma_f32_16x16x32_bf16(a[i], b[j], acc[i][j], 0, 0, 0);
    }
#pragma unroll
    for (int i = 0; i < 2; i++)
#pragma unroll
        for (int j = 0; j < 2; j++)
#pragma unroll
            for (int r = 0; r < 4; r++) {
                int row = r0 + wr * 32 + i * 16 + g * 4 + r;
                int col = c0 + wc * 32 + j * 16 + ln;
                out[(size_t)row * DM + col] = acc[i][j][r] + qres[(size_t)row * DM + col];
            }
}

extern "C" void kernel_launch(void* const* d_in, const int* in_sizes, int n_in,
                              void* d_out, int out_size, void* d_ws, size_t ws_size,
                              hipStream_t stream) {
    (void)in_sizes; (void)n_in; (void)out_size; (void)ws_size;
    const float* q     = (const float*)d_in[0];
    const float* k     = (const float*)d_in[1];
    const float* v     = (const float*)d_in[2];
    const float* wqs   = (const float*)d_in[3];
    const float* wks   = (const float*)d_in[4];
    const float* wvs   = (const float*)d_in[5];
    const float* wfc   = (const float*)d_in[6];
    const float* km    = (const float*)d_in[7];
    const float* qm    = (const float*)d_in[8];
    const float* mm    = (const float*)d_in[9];
    const float* prior = (const float*)d_in[10];

    char* ws = (char*)d_ws;
    short* WT   = (short*)(ws);                  // 4 x 512 x 512 bf16 = 2 MiB
    short* QHb  = (short*)(ws + 2097152);        // 4096 x 512 bf16   = 4 MiB
    short* KHb  = (short*)(ws + 6291456);        // 8192 x 512 bf16   = 8 MiB
    short* VT   = (short*)(ws + 14680064);       // (H*B*64) x 1024   = 8 MiB
    float* logp = (float*)(ws + 23068672);       // 8x512x1024 f32    = 16 MiB
    short* outh = (short*)(ws + 39845888);       // 4096 x 512 bf16   = 4 MiB

    float* out     = (float*)d_out;
    float* p_out   = out + 2097152;
    float* raw_out = p_out + 33554432;
    float* lgp_out = raw_out + 33554432;

    castw_kernel<<<dim3(16, 16, 4), dim3(32, 8), 0, stream>>>(wqs, wks, wvs, wfc, WT);
    prior_kernel<<<dim3(32, 16, 8), dim3(32, 8), 0, stream>>>(prior, logp);
    proj_kernel<0><<<dim3(64, 8),  256, 0, stream>>>(q, WT,          QHb);
    proj_kernel<0><<<dim3(128, 8), 256, 0, stream>>>(k, WT + 262144, KHb);
    proj_kernel<1><<<dim3(128, 8), 256, 0, stream>>>(v, WT + 524288, VT);
    attn_kernel<<<dim3(32, 8, 8), 256, 0, stream>>>(QHb, KHb, VT, logp, km, qm, mm,
                                                    p_out, raw_out, lgp_out, outh);
    final_kernel<<<dim3(64, 8), 256, 0, stream>>>(outh, WT + 786432, q, out);
}

// Round 2
// 331.794 us; speedup vs baseline: 1.2351x; 1.2351x over previous
//
#include <hip/hip_runtime.h>

#define H   8
#define DK  64
#define DV  64
#define DM  512
#define B_  8
#define LQ  512
#define LK  1024
#define NEG (-1e30f)

typedef __attribute__((ext_vector_type(8))) short bf16x8;
typedef __attribute__((ext_vector_type(4))) float f32x4;

__device__ __forceinline__ short f2bf(float f) {
    union { float f; unsigned u; } x; x.f = f;
    unsigned r = x.u + 0x7fffu + ((x.u >> 16) & 1u);
    return (short)(r >> 16);
}

// ---------------- kernel 1: cast + transpose the 4 weight matrices ----------
// WT[mat][n][k] = bf16(w[mat][k][n]),  each 512x512
__global__ __launch_bounds__(256) void castw_kernel(
    const float* __restrict__ wqs, const float* __restrict__ wks,
    const float* __restrict__ wvs, const float* __restrict__ wfc,
    short* __restrict__ WT) {
    __shared__ float tile[32][33];
    int mat = blockIdx.z;
    const float* src = (mat == 0) ? wqs : (mat == 1) ? wks : (mat == 2) ? wvs : wfc;
    short* dst = WT + (size_t)mat * DM * DM;
    int k0 = blockIdx.x * 32, n0 = blockIdx.y * 32;
    int tx = threadIdx.x, ty = threadIdx.y;
#pragma unroll
    for (int i = 0; i < 4; i++)
        tile[ty + i * 8][tx] = src[(size_t)(k0 + ty + i * 8) * DM + n0 + tx];
    __syncthreads();
#pragma unroll
    for (int i = 0; i < 4; i++)
        dst[(size_t)(n0 + ty + i * 8) * DM + k0 + tx] = f2bf(tile[tx][ty + i * 8]);
}

// ---------------- kernel 2: transpose the attention prior (no log now) ------
// prt[b][q][k] = prior[b][k][q]
__global__ __launch_bounds__(256) void prior_kernel(
    const float* __restrict__ prior, float* __restrict__ prt) {
    __shared__ float tile[32][33];
    int b = blockIdx.z, k0 = blockIdx.x * 32, q0 = blockIdx.y * 32;
    int tx = threadIdx.x, ty = threadIdx.y;
    const float* src = prior + (size_t)b * LK * LQ;
    float* dst = prt + (size_t)b * LQ * LK;
#pragma unroll
    for (int i = 0; i < 4; i++)
        tile[ty + i * 8][tx] = src[(size_t)(k0 + ty + i * 8) * LQ + q0 + tx];
    __syncthreads();
#pragma unroll
    for (int i = 0; i < 4; i++)
        dst[(size_t)(q0 + ty + i * 8) * LK + k0 + tx] = tile[tx][ty + i * 8];
}

// ---------------- kernel 3: projections (X fp32 @ WT^T) -> bf16 -------------
// MODE 0: out[row][col] natural (ld = 512)
// MODE 1: V transposed per-head: out[((col/64)*B + row/1024)*64 + col%64][row%1024]
template <int MODE>
__global__ __launch_bounds__(256) void proj_kernel(
    const float* __restrict__ X, const short* __restrict__ WT,
    short* __restrict__ out) {
    int tid = threadIdx.x;
    int wid = tid >> 6, lane = tid & 63, g = lane >> 4, ln = lane & 15;
    int wr = wid >> 1, wc = wid & 1;
    int r0 = blockIdx.x * 64, c0 = blockIdx.y * 64;
    f32x4 acc[2][2] = {};
    for (int kb = 0; kb < 16; kb++) {
        bf16x8 a[2], b[2];
#pragma unroll
        for (int i = 0; i < 2; i++) {
            int row = r0 + wr * 32 + i * 16 + ln;
            const float* xp = X + (size_t)row * DM + kb * 32 + g * 8;
            float4 x0 = *(const float4*)xp;
            float4 x1 = *(const float4*)(xp + 4);
            bf16x8 av;
            av[0] = f2bf(x0.x); av[1] = f2bf(x0.y); av[2] = f2bf(x0.z); av[3] = f2bf(x0.w);
            av[4] = f2bf(x1.x); av[5] = f2bf(x1.y); av[6] = f2bf(x1.z); av[7] = f2bf(x1.w);
            a[i] = av;
        }
#pragma unroll
        for (int j = 0; j < 2; j++) {
            int col = c0 + wc * 32 + j * 16 + ln;
            b[j] = *(const bf16x8*)(WT + (size_t)col * DM + kb * 32 + g * 8);
        }
#pragma unroll
        for (int i = 0; i < 2; i++)
#pragma unroll
            for (int j = 0; j < 2; j++)
                acc[i][j] = __builtin_amdgcn_mfma_f32_16x16x32_bf16(a[i], b[j], acc[i][j], 0, 0, 0);
    }
#pragma unroll
    for (int i = 0; i < 2; i++)
#pragma unroll
        for (int j = 0; j < 2; j++) {
            int colg = c0 + wc * 32 + j * 16 + ln;
            if (MODE == 0) {
#pragma unroll
                for (int r = 0; r < 4; r++) {
                    int rowg = r0 + wr * 32 + i * 16 + g * 4 + r;
                    out[(size_t)rowg * DM + colg] = f2bf(acc[i][j][r]);
                }
            } else {
                int hh = colg >> 6, d = colg & 63;
                int rbase = r0 + wr * 32 + i * 16 + g * 4;
                int bb = rbase >> 10, kk = rbase & 1023;
                union { short s[4]; unsigned long long u; } pk;
#pragma unroll
                for (int r = 0; r < 4; r++) pk.s[r] = f2bf(acc[i][j][r]);
                *(unsigned long long*)(out + ((size_t)((hh * B_ + bb) * DV + d)) * LK + kk) = pk.u;
            }
        }
}

// ---------------- kernel 4: fused attention (single pass, swapped QK^T) -----
// Swapped MFMA: D[k_sub][q] with lane = g*16+ln -> q = q0+ln, k = k0+g*4+r.
// Each lane owns 4 consecutive k for one q row -> float4 mask loads + stores.
__global__ __launch_bounds__(256, 4) void attn_kernel(
    const short* __restrict__ QHb, const short* __restrict__ KHb,
    const short* __restrict__ VT, const float* __restrict__ prt,
    const float* __restrict__ km, const float* __restrict__ qm,
    const float* __restrict__ mm, float* __restrict__ p_out,
    float* __restrict__ raw_out, float* __restrict__ lgp_out,
    short* __restrict__ outh) {
    __shared__ short ptile[16][LK + 8];
    __shared__ float red[4][16][2];
    int tid = threadIdx.x;
    int wid = tid >> 6, lane = tid & 63, g = lane >> 4, ln = lane & 15;
    int q0 = blockIdx.x * 16, b = blockIdx.y, h = blockIdx.z;
    int kw0 = wid * 256;

    // Q fragments (B operand): lane ln holds q-row q0+ln
    bf16x8 bq0, bq1;
    {
        const short* qp = QHb + ((size_t)(b * LQ + q0 + ln)) * DM + h * DK + g * 8;
        bq0 = *(const bf16x8*)qp;
        bq1 = *(const bf16x8*)(qp + 32);
    }

    const size_t mrow = ((size_t)(b * LQ + q0 + ln)) * LK;

    // ---- single pass over this wave's 256 k: scores + numerators in regs ----
    float s1 = 0.f, s2 = 0.f;
    f32x4 x[16];
#pragma unroll
    for (int kt = 0; kt < 16; kt++) {
        int k0 = kw0 + kt * 16;
        const short* kp = KHb + ((size_t)(b * LK + k0 + ln)) * DM + h * DK + g * 8;
        bf16x8 ak0 = *(const bf16x8*)kp;
        bf16x8 ak1 = *(const bf16x8*)(kp + 32);
        f32x4 sa = {0.f, 0.f, 0.f, 0.f};
        sa = __builtin_amdgcn_mfma_f32_16x16x32_bf16(ak0, bq0, sa, 0, 0, 0);
        sa = __builtin_amdgcn_mfma_f32_16x16x32_bf16(ak1, bq1, sa, 0, 0, 0);
        float4 km4 = *(const float4*)(km + mrow + k0 + g * 4);
        float4 pr4 = *(const float4*)(prt + mrow + k0 + g * 4);
        f32x4 xv;
#pragma unroll
        for (int r = 0; r < 4; r++) {
            float kmr = (r == 0) ? km4.x : (r == 1) ? km4.y : (r == 2) ? km4.z : km4.w;
            float prr = (r == 0) ? pr4.x : (r == 1) ? pr4.y : (r == 2) ? pr4.z : pr4.w;
            float e = (kmr == 0.0f) ? 0.0f : __expf(sa[r] * 0.125f - 16.0f);
            float xr = e * (prr + 1e-8f);
            s1 += e;
            s2 += xr;
            xv[r] = xr;
        }
        x[kt] = xv;
    }

    // ---- reduce across g (same wave) then across the 4 waves ----
    s1 += __shfl_xor(s1, 16, 64); s1 += __shfl_xor(s1, 32, 64);
    s2 += __shfl_xor(s2, 16, 64); s2 += __shfl_xor(s2, 32, 64);
    if (g == 0) { red[wid][ln][0] = s1; red[wid][ln][1] = s2; }
    __syncthreads();
    float t1 = red[0][ln][0] + red[1][ln][0] + red[2][ln][0] + red[3][ln][0];
    float t2 = red[0][ln][1] + red[1][ln][1] + red[2][ln][1] + red[3][ln][1];
    float inv1 = 1.0f / t1;
    float inv2 = 1.0f / t2;
    float qmv = qm[b * LQ + q0 + ln];

    // ---- output pass: all from registers, float4 stores ----
    const size_t obase = ((size_t)((h * B_ + b) * LQ + q0 + ln)) * LK;
#pragma unroll
    for (int kt = 0; kt < 16; kt++) {
        int k0 = kw0 + kt * 16;
        float4 mm4 = *(const float4*)(mm + mrow + k0 + g * 4);
        float4 pw, rw, lw;
        union { short s[4]; unsigned long long u; } pk;
#pragma unroll
        for (int r = 0; r < 4; r++) {
            float mmr = (r == 0) ? mm4.x : (r == 1) ? mm4.y : (r == 2) ? mm4.z : mm4.w;
            float xr = x[kt][r];
            float p0 = xr * inv2;
            float praw = p0 * qmv;
            float pfin = praw * mmr;
            float lgp = fmaxf(__logf(xr * inv1), -1e30f);
            ((float*)&pw)[r] = pfin;
            ((float*)&rw)[r] = praw;
            ((float*)&lw)[r] = lgp;
            pk.s[r] = f2bf(pfin);
        }
        size_t oidx = obase + k0 + g * 4;
        *(float4*)(p_out + oidx)   = pw;
        *(float4*)(raw_out + oidx) = rw;
        *(float4*)(lgp_out + oidx) = lw;
        *(unsigned long long*)(&ptile[ln][k0 + g * 4]) = pk.u;
    }
    __syncthreads();

    // ---- PV: each wave owns a 16-wide d-slice, full K ----
    f32x4 oacc = {0.f, 0.f, 0.f, 0.f};
    int d0 = wid * 16;
    const short* vrow = VT + ((size_t)((h * B_ + b) * DV + d0 + ln)) * LK;
    for (int kc = 0; kc < 32; kc++) {
        bf16x8 ap = *(const bf16x8*)(&ptile[ln][kc * 32 + g * 8]);
        bf16x8 bv = *(const bf16x8*)(vrow + kc * 32 + g * 8);
        oacc = __builtin_amdgcn_mfma_f32_16x16x32_bf16(ap, bv, oacc, 0, 0, 0);
    }
#pragma unroll
    for (int r = 0; r < 4; r++) {
        int row = q0 + g * 4 + r;
        outh[((size_t)(b * LQ + row)) * DM + h * DV + d0 + ln] = f2bf(oacc[r]);
    }
}

// ---------------- kernel 5: out = outh @ w_fc + residual --------------------
__global__ __launch_bounds__(256) void final_kernel(
    const short* __restrict__ outh, const short* __restrict__ WTfc,
    const float* __restrict__ qres, float* __restrict__ out) {
    int tid = threadIdx.x;
    int wid = tid >> 6, lane = tid & 63, g = lane >> 4, ln = lane & 15;
    int wr = wid >> 1, wc = wid & 1;
    int r0 = blockIdx.x * 64, c0 = blockIdx.y * 64;
    f32x4 acc[2][2] = {};
    for (int kb = 0; kb < 16; kb++) {
        bf16x8 a[2], b[2];
#pragma unroll
        for (int i = 0; i < 2; i++)
            a[i] = *(const bf16x8*)(outh + ((size_t)(r0 + wr * 32 + i * 16 + ln)) * DM + kb * 32 + g * 8);
#pragma unroll
        for (int j = 0; j < 2; j++)
            b[j] = *(const bf16x8*)(WTfc + ((size_t)(c0 + wc * 32 + j * 16 + ln)) * DM + kb * 32 + g * 8);
#pragma unroll
        for (int i = 0; i < 2; i++)
#pragma unroll
            for (int j = 0; j < 2; j++)
                acc[i][j] = __builtin_amdgcn_mfma_f32_16x16x32_bf16(a[i], b[j], acc[i][j], 0, 0, 0);
    }
#pragma unroll
    for (int i = 0; i < 2; i++)
#pragma unroll
        for (int j = 0; j < 2; j++)
#pragma unroll
            for (int r = 0; r < 4; r++) {
                int row = r0 + wr * 32 + i * 16 + g * 4 + r;
                int col = c0 + wc * 32 + j * 16 + ln;
                out[(size_t)row * DM + col] = acc[i][j][r] + qres[(size_t)row * DM + col];
            }
}

extern "C" void kernel_launch(void* const* d_in, const int* in_sizes, int n_in,
                              void* d_out, int out_size, void* d_ws, size_t ws_size,
                              hipStream_t stream) {
    (void)in_sizes; (void)n_in; (void)out_size; (void)ws_size;
    const float* q     = (const float*)d_in[0];
    const float* k     = (const float*)d_in[1];
    const float* v     = (const float*)d_in[2];
    const float* wqs   = (const float*)d_in[3];
    const float* wks   = (const float*)d_in[4];
    const float* wvs   = (const float*)d_in[5];
    const float* wfc   = (const float*)d_in[6];
    const float* km    = (const float*)d_in[7];
    const float* qm    = (const float*)d_in[8];
    const float* mm    = (const float*)d_in[9];
    const float* prior = (const float*)d_in[10];

    char* ws = (char*)d_ws;
    short* WT   = (short*)(ws);                  // 4 x 512 x 512 bf16 = 2 MiB
    short* QHb  = (short*)(ws + 2097152);        // 4096 x 512 bf16   = 4 MiB
    short* KHb  = (short*)(ws + 6291456);        // 8192 x 512 bf16   = 8 MiB
    short* VT   = (short*)(ws + 14680064);       // (H*B*64) x 1024   = 8 MiB
    float* prt  = (float*)(ws + 23068672);       // 8x512x1024 f32    = 16 MiB
    short* outh = (short*)(ws + 39845888);       // 4096 x 512 bf16   = 4 MiB

    float* out     = (float*)d_out;
    float* p_out   = out + 2097152;
    float* raw_out = p_out + 33554432;
    float* lgp_out = raw_out + 33554432;

    castw_kernel<<<dim3(16, 16, 4), dim3(32, 8), 0, stream>>>(wqs, wks, wvs, wfc, WT);
    prior_kernel<<<dim3(32, 16, 8), dim3(32, 8), 0, stream>>>(prior, prt);
    proj_kernel<0><<<dim3(64, 8),  256, 0, stream>>>(q, WT,          QHb);
    proj_kernel<0><<<dim3(128, 8), 256, 0, stream>>>(k, WT + 262144, KHb);
    proj_kernel<1><<<dim3(128, 8), 256, 0, stream>>>(v, WT + 524288, VT);
    attn_kernel<<<dim3(32, 8, 8), 256, 0, stream>>>(QHb, KHb, VT, prt, km, qm, mm,
                                                    p_out, raw_out, lgp_out, outh);
    final_kernel<<<dim3(64, 8), 256, 0, stream>>>(outh, WT + 786432, q, out);
}